// Round 1
// baseline (609.647 us; speedup 1.0000x reference)
//
#include <hip/hip_runtime.h>
#include <hip/hip_bf16.h>
#include <stdint.h>

#define NSP 16384   // 128*128 spatial
#define BATCH 4
#define EPSV 1e-6f

typedef __attribute__((ext_vector_type(8))) short fragAB;   // 8 bf16
typedef __attribute__((ext_vector_type(4))) float fragC;    // 4 fp32

__device__ __forceinline__ unsigned short f2bf(float f) {
    union { float f; unsigned u; } un; un.f = f;
    unsigned r = un.u + 0x7fffu + ((un.u >> 16) & 1u);   // RNE
    return (unsigned short)(r >> 16);
}

#define GLD_LDS(g, l) __builtin_amdgcn_global_load_lds( \
    (const __attribute__((address_space(1))) void*)(g), \
    (__attribute__((address_space(3))) void*)(l), 16, 0, 0)

// ---------------- x (B,C,N) fp32 -> xt (B,N,C) bf16 ----------------
__global__ __launch_bounds__(256) void transpose_x(const float* __restrict__ x,
                                                   unsigned short* __restrict__ xt) {
    __shared__ float lds[64 * 65];
    const int b  = blockIdx.z;
    const int c0 = blockIdx.y * 64;
    const int n0 = blockIdx.x * 64;
    const int t  = threadIdx.x;
    const int nl = (t & 15) * 4;
    const int cl = t >> 4;
#pragma unroll
    for (int i = 0; i < 4; ++i) {
        int c = cl + i * 16;
        float4 v = *(const float4*)&x[((size_t)(b * 512 + c0 + c)) * NSP + n0 + nl];
        float* row = &lds[c * 65 + nl];
        row[0] = v.x; row[1] = v.y; row[2] = v.z; row[3] = v.w;
    }
    __syncthreads();
#pragma unroll
    for (int i = 0; i < 2; ++i) {
        int ch = t + i * 256;      // 0..511
        int n  = ch >> 3;
        int co = (ch & 7) * 8;
        unsigned v0 = 0, v1 = 0, v2 = 0, v3 = 0;
        v0 = f2bf(lds[(co + 0) * 65 + n]) | ((unsigned)f2bf(lds[(co + 1) * 65 + n]) << 16);
        v1 = f2bf(lds[(co + 2) * 65 + n]) | ((unsigned)f2bf(lds[(co + 3) * 65 + n]) << 16);
        v2 = f2bf(lds[(co + 4) * 65 + n]) | ((unsigned)f2bf(lds[(co + 5) * 65 + n]) << 16);
        v3 = f2bf(lds[(co + 6) * 65 + n]) | ((unsigned)f2bf(lds[(co + 7) * 65 + n]) << 16);
        uint4 pk; pk.x = v0; pk.y = v1; pk.z = v2; pk.w = v3;
        *(uint4*)&xt[((size_t)(b * NSP + n0 + n)) * 512 + c0 + co] = pk;
    }
}

// ---------------- fp32 -> bf16 convert (w_qkv) ----------------
__global__ __launch_bounds__(256) void convert_w(const float* __restrict__ w,
                                                 unsigned short* __restrict__ wb) {
    int i = (blockIdx.x * 256 + threadIdx.x) * 4;
    float4 v = *(const float4*)&w[i];
    uint2 pk;
    pk.x = f2bf(v.x) | ((unsigned)f2bf(v.y) << 16);
    pk.y = f2bf(v.z) | ((unsigned)f2bf(v.w) << 16);
    *(uint2*)&wb[i] = pk;
}

// ---------------- qkv GEMM: (B,N,512)bf16 @ (1536,512)^T + bias ----------------
// q -> qbuf (B,512,N) relu ; k -> kbuf (B,512,N) relu ; v -> vbuf (B,N,512)
__global__ __launch_bounds__(256) void gemm_qkv(
    const unsigned short* __restrict__ xt, const unsigned short* __restrict__ wq,
    const float* __restrict__ bqkv,
    unsigned short* __restrict__ qbuf, unsigned short* __restrict__ kbuf,
    unsigned short* __restrict__ vbuf) {
    __shared__ unsigned short Als[128 * 64];
    __shared__ unsigned short Bls[128 * 64];
    const int b  = blockIdx.z;
    const int n0 = blockIdx.x * 128;
    const int j0 = blockIdx.y * 128;
    const int t  = threadIdx.x;
    const int wv = t >> 6, ln = t & 63;
    const unsigned short* Ag = xt + (size_t)(b * NSP + n0) * 512;
    const unsigned short* Bg = wq + (size_t)j0 * 512;

    fragC acc[4][4];
#pragma unroll
    for (int i = 0; i < 4; ++i)
#pragma unroll
        for (int j = 0; j < 4; ++j) { acc[i][j][0]=0.f; acc[i][j][1]=0.f; acc[i][j][2]=0.f; acc[i][j][3]=0.f; }

    const int mw = (wv >> 1) * 64, nw = (wv & 1) * 64;
    const int srow = ln >> 3, scol = (ln & 7) * 8;

    for (int k0 = 0; k0 < 512; k0 += 64) {
#pragma unroll
        for (int i = 0; i < 4; ++i) {
            int chunk = wv * 4 + i;                 // 16 chunks of 8 rows
            int row = chunk * 8 + srow;
            GLD_LDS(Ag + (size_t)row * 512 + k0 + scol, &Als[chunk * 512]);
            GLD_LDS(Bg + (size_t)row * 512 + k0 + scol, &Bls[chunk * 512]);
        }
        __syncthreads();
#pragma unroll
        for (int kk = 0; kk < 64; kk += 32) {
            fragAB a[4], bf[4];
#pragma unroll
            for (int mt = 0; mt < 4; ++mt)
                a[mt] = *(const fragAB*)&Als[(mw + mt * 16 + (ln & 15)) * 64 + kk + (ln >> 4) * 8];
#pragma unroll
            for (int nt = 0; nt < 4; ++nt)
                bf[nt] = *(const fragAB*)&Bls[(nw + nt * 16 + (ln & 15)) * 64 + kk + (ln >> 4) * 8];
#pragma unroll
            for (int mt = 0; mt < 4; ++mt)
#pragma unroll
                for (int nt = 0; nt < 4; ++nt)
                    acc[mt][nt] = __builtin_amdgcn_mfma_f32_16x16x32_bf16(a[mt], bf[nt], acc[mt][nt], 0, 0, 0);
        }
        __syncthreads();
    }

    const int sec = j0 >> 9;  // 0=q,1=k,2=v (tiles never straddle: 512%128==0)
    if (sec < 2) {
        unsigned short* dst = (sec == 0 ? qbuf : kbuf) + (size_t)b * 512 * NSP;
#pragma unroll
        for (int mt = 0; mt < 4; ++mt)
#pragma unroll
            for (int nt = 0; nt < 4; ++nt) {
                int j  = j0 + nw + nt * 16 + (ln & 15);
                int ch = j & 511;
                int n  = n0 + mw + mt * 16 + (ln >> 4) * 4;
                float bias = bqkv[j];
                float r0 = acc[mt][nt][0] + bias; r0 = r0 > 0.f ? r0 : 0.f;
                float r1 = acc[mt][nt][1] + bias; r1 = r1 > 0.f ? r1 : 0.f;
                float r2 = acc[mt][nt][2] + bias; r2 = r2 > 0.f ? r2 : 0.f;
                float r3 = acc[mt][nt][3] + bias; r3 = r3 > 0.f ? r3 : 0.f;
                uint2 pk;
                pk.x = f2bf(r0) | ((unsigned)f2bf(r1) << 16);
                pk.y = f2bf(r2) | ((unsigned)f2bf(r3) << 16);
                *(uint2*)&dst[(size_t)ch * NSP + n] = pk;
            }
    } else {
#pragma unroll
        for (int mt = 0; mt < 4; ++mt)
#pragma unroll
            for (int nt = 0; nt < 4; ++nt) {
                int j  = j0 + nw + nt * 16 + (ln & 15);
                int ch = j & 511;
                int n  = n0 + mw + mt * 16 + (ln >> 4) * 4;
                float bias = bqkv[j];
#pragma unroll
                for (int r = 0; r < 4; ++r)
                    vbuf[((size_t)(b * NSP + n + r)) * 512 + ch] = f2bf(acc[mt][nt][r] + bias);
            }
    }
}

// ---------------- kq[b,h,c,d] = sum_n k*q  (split-K, atomic fp32) ----------------
__global__ __launch_bounds__(256) void kq_kernel(
    const unsigned short* __restrict__ kbuf, const unsigned short* __restrict__ qbuf,
    float* __restrict__ kq) {
    const int bh = blockIdx.x;      // 0..31
    const int chunk = blockIdx.y;   // 0..15
    const int t = threadIdx.x, wv = t >> 6, ln = t & 63;
    const unsigned short* Kg = kbuf + (size_t)(bh * 64) * NSP;
    const unsigned short* Qg = qbuf + (size_t)(bh * 64) * NSP;
    fragC acc[4];
#pragma unroll
    for (int i = 0; i < 4; ++i) { acc[i][0]=0.f; acc[i][1]=0.f; acc[i][2]=0.f; acc[i][3]=0.f; }
    const int arow = wv * 16 + (ln & 15);
    const int koff = (ln >> 4) * 8;
    const int nbeg = chunk * 1024;
    for (int n = nbeg; n < nbeg + 1024; n += 32) {
        fragAB a = *(const fragAB*)&Kg[(size_t)arow * NSP + n + koff];
#pragma unroll
        for (int dt = 0; dt < 4; ++dt) {
            fragAB bq = *(const fragAB*)&Qg[(size_t)(dt * 16 + (ln & 15)) * NSP + n + koff];
            acc[dt] = __builtin_amdgcn_mfma_f32_16x16x32_bf16(a, bq, acc[dt], 0, 0, 0);
        }
    }
    float* kqb = kq + bh * 4096;
#pragma unroll
    for (int dt = 0; dt < 4; ++dt) {
        int d = dt * 16 + (ln & 15);
#pragma unroll
        for (int r = 0; r < 4; ++r) {
            int c = wv * 16 + (ln >> 4) * 4 + r;
            atomicAdd(&kqb[c * 64 + d], acc[dt][r]);
        }
    }
}

// ---------------- W2[b,j,h*64+c] = sum_d w_out[j,d*8+h]*kq[b,h,c,d]/norm[b,h,d] ----------------
__global__ __launch_bounds__(256) void w2_kernel(
    const float* __restrict__ kq, const float* __restrict__ wout,
    unsigned short* __restrict__ W2) {
    __shared__ float wsc[512];
    const int j = blockIdx.x, b = blockIdx.y, t = threadIdx.x;
    const float* kqb = kq + b * 32768;
#pragma unroll
    for (int i = 0; i < 2; ++i) {
        int idx = t + i * 256;
        int h = idx >> 6, d = idx & 63;
        float s = EPSV;
        for (int c = 0; c < 64; ++c) s += kqb[(h * 64 + c) * 64 + d];
        wsc[idx] = wout[j * 512 + d * 8 + h] / s;
    }
    __syncthreads();
#pragma unroll
    for (int i = 0; i < 2; ++i) {
        int hc = t + i * 256;
        int h = hc >> 6, c = hc & 63;
        const float* kr = &kqb[(h * 64 + c) * 64];
        const float* wr = &wsc[h * 64];
        float a = 0.f;
        for (int d = 0; d < 64; ++d) a += wr[d] * kr[d];
        W2[((size_t)(b * 512 + j)) * 512 + hc] = f2bf(a);
    }
}

// ---------------- out GEMM: out[b,j,n] = sum_hc v[b,n,hc]*W2[b,j,hc] + b_out[j] ----------------
__global__ __launch_bounds__(256) void gemm_out(
    const unsigned short* __restrict__ vbuf, const unsigned short* __restrict__ W2,
    const float* __restrict__ bout, float* __restrict__ out) {
    __shared__ unsigned short Als[128 * 64];
    __shared__ unsigned short Bls[128 * 64];
    const int b  = blockIdx.z;
    const int n0 = blockIdx.x * 128;
    const int j0 = blockIdx.y * 128;
    const int t  = threadIdx.x;
    const int wv = t >> 6, ln = t & 63;
    const unsigned short* Ag = vbuf + (size_t)(b * NSP + n0) * 512;
    const unsigned short* Bg = W2 + (size_t)(b * 512 + j0) * 512;

    fragC acc[4][4];
#pragma unroll
    for (int i = 0; i < 4; ++i)
#pragma unroll
        for (int j = 0; j < 4; ++j) { acc[i][j][0]=0.f; acc[i][j][1]=0.f; acc[i][j][2]=0.f; acc[i][j][3]=0.f; }

    const int mw = (wv >> 1) * 64, nw = (wv & 1) * 64;
    const int srow = ln >> 3, scol = (ln & 7) * 8;

    for (int k0 = 0; k0 < 512; k0 += 64) {
#pragma unroll
        for (int i = 0; i < 4; ++i) {
            int chunk = wv * 4 + i;
            int row = chunk * 8 + srow;
            GLD_LDS(Ag + (size_t)row * 512 + k0 + scol, &Als[chunk * 512]);
            GLD_LDS(Bg + (size_t)row * 512 + k0 + scol, &Bls[chunk * 512]);
        }
        __syncthreads();
#pragma unroll
        for (int kk = 0; kk < 64; kk += 32) {
            fragAB a[4], bf[4];
#pragma unroll
            for (int mt = 0; mt < 4; ++mt)
                a[mt] = *(const fragAB*)&Als[(mw + mt * 16 + (ln & 15)) * 64 + kk + (ln >> 4) * 8];
#pragma unroll
            for (int nt = 0; nt < 4; ++nt)
                bf[nt] = *(const fragAB*)&Bls[(nw + nt * 16 + (ln & 15)) * 64 + kk + (ln >> 4) * 8];
#pragma unroll
            for (int mt = 0; mt < 4; ++mt)
#pragma unroll
                for (int nt = 0; nt < 4; ++nt)
                    acc[mt][nt] = __builtin_amdgcn_mfma_f32_16x16x32_bf16(a[mt], bf[nt], acc[mt][nt], 0, 0, 0);
        }
        __syncthreads();
    }

#pragma unroll
    for (int mt = 0; mt < 4; ++mt)
#pragma unroll
        for (int nt = 0; nt < 4; ++nt) {
            int j = j0 + nw + nt * 16 + (ln & 15);
            int n = n0 + mw + mt * 16 + (ln >> 4) * 4;
            float bias = bout[j];
            float4 v;
            v.x = acc[mt][nt][0] + bias;
            v.y = acc[mt][nt][1] + bias;
            v.z = acc[mt][nt][2] + bias;
            v.w = acc[mt][nt][3] + bias;
            *(float4*)&out[((size_t)(b * 512 + j)) * NSP + n] = v;
        }
}

extern "C" void kernel_launch(void* const* d_in, const int* in_sizes, int n_in,
                              void* d_out, int out_size, void* d_ws, size_t ws_size,
                              hipStream_t stream) {
    const float* x    = (const float*)d_in[0];
    const float* wqkv = (const float*)d_in[1];
    const float* bqkv = (const float*)d_in[2];
    const float* wout = (const float*)d_in[3];
    const float* bout = (const float*)d_in[4];
    float* out = (float*)d_out;

    char* p = (char*)d_ws;
    unsigned short* xt   = (unsigned short*)p; p += (size_t)BATCH * NSP * 512 * 2;   // 64 MB
    unsigned short* wqb  = (unsigned short*)p; p += (size_t)1536 * 512 * 2;
    unsigned short* qbuf = (unsigned short*)p; p += (size_t)BATCH * 512 * NSP * 2;   // 64 MB
    unsigned short* kbuf = (unsigned short*)p; p += (size_t)BATCH * 512 * NSP * 2;   // 64 MB
    unsigned short* vbuf = (unsigned short*)p; p += (size_t)BATCH * NSP * 512 * 2;   // 64 MB
    float*          kq   = (float*)p;          p += (size_t)BATCH * 8 * 64 * 64 * 4; // 512 KB
    unsigned short* W2   = (unsigned short*)p; p += (size_t)BATCH * 512 * 512 * 2;   // 2 MB

    hipMemsetAsync(kq, 0, (size_t)BATCH * 8 * 64 * 64 * 4, stream);
    transpose_x<<<dim3(256, 8, BATCH), 256, 0, stream>>>(x, xt);
    convert_w<<<dim3(768), 256, 0, stream>>>(wqkv, wqb);
    gemm_qkv<<<dim3(128, 12, BATCH), 256, 0, stream>>>(xt, wqb, bqkv, qbuf, kbuf, vbuf);
    kq_kernel<<<dim3(32, 16), 256, 0, stream>>>(kbuf, qbuf, kq);
    w2_kernel<<<dim3(512, BATCH), 256, 0, stream>>>(kq, wout, W2);
    gemm_out<<<dim3(128, 4, BATCH), 256, 0, stream>>>(vbuf, W2, bout, out);
}

// Round 2
// 519.533 us; speedup vs baseline: 1.1735x; 1.1735x over previous
//
#include <hip/hip_runtime.h>
#include <hip/hip_bf16.h>
#include <stdint.h>

#define NSP 16384   // 128*128 spatial
#define BATCH 4
#define EPSV 1e-6f

typedef __attribute__((ext_vector_type(8))) short fragAB;   // 8 bf16
typedef __attribute__((ext_vector_type(4))) float fragC;    // 4 fp32

__device__ __forceinline__ unsigned short f2bf(float f) {
    union { float f; unsigned u; } un; un.f = f;
    unsigned r = un.u + 0x7fffu + ((un.u >> 16) & 1u);   // RNE
    return (unsigned short)(r >> 16);
}

#define GLD_LDS(g, l) __builtin_amdgcn_global_load_lds( \
    (const __attribute__((address_space(1))) void*)(g), \
    (__attribute__((address_space(3))) void*)(l), 16, 0, 0)

// XOR-swizzled fragment read. Element (row m, colgroup g of 8 shorts) lives at
// (m>>3)*512 + (m&7)*64 + ((g ^ (m&7))*8)  — matches global_load_lds lane slots
// when staging lane ln loads colgroup (ln&7)^(ln>>3) of row (chunk*8 + (ln>>3)).
__device__ __forceinline__ fragAB ldfrag(const unsigned short* ls, int m, int g) {
    return *(const fragAB*)&ls[((m >> 3) << 9) + ((m & 7) << 6) + ((g ^ (m & 7)) << 3)];
}

// ---------------- x (B,C,N) fp32 -> xt (B,N,C) bf16 ----------------
__global__ __launch_bounds__(256) void transpose_x(const float* __restrict__ x,
                                                   unsigned short* __restrict__ xt) {
    __shared__ float lds[64 * 65];
    const int b  = blockIdx.z;
    const int c0 = blockIdx.y * 64;
    const int n0 = blockIdx.x * 64;
    const int t  = threadIdx.x;
    const int nl = (t & 15) * 4;
    const int cl = t >> 4;
#pragma unroll
    for (int i = 0; i < 4; ++i) {
        int c = cl + i * 16;
        float4 v = *(const float4*)&x[((size_t)(b * 512 + c0 + c)) * NSP + n0 + nl];
        float* row = &lds[c * 65 + nl];
        row[0] = v.x; row[1] = v.y; row[2] = v.z; row[3] = v.w;
    }
    __syncthreads();
#pragma unroll
    for (int i = 0; i < 2; ++i) {
        int ch = t + i * 256;      // 0..511
        int n  = ch >> 3;
        int co = (ch & 7) * 8;
        unsigned v0, v1, v2, v3;
        v0 = f2bf(lds[(co + 0) * 65 + n]) | ((unsigned)f2bf(lds[(co + 1) * 65 + n]) << 16);
        v1 = f2bf(lds[(co + 2) * 65 + n]) | ((unsigned)f2bf(lds[(co + 3) * 65 + n]) << 16);
        v2 = f2bf(lds[(co + 4) * 65 + n]) | ((unsigned)f2bf(lds[(co + 5) * 65 + n]) << 16);
        v3 = f2bf(lds[(co + 6) * 65 + n]) | ((unsigned)f2bf(lds[(co + 7) * 65 + n]) << 16);
        uint4 pk; pk.x = v0; pk.y = v1; pk.z = v2; pk.w = v3;
        *(uint4*)&xt[((size_t)(b * NSP + n0 + n)) * 512 + c0 + co] = pk;
    }
}

// ---------------- wqkv rows 0..1023 fp32 -> bf16 ----------------
__global__ __launch_bounds__(256) void convert_w(const float* __restrict__ w,
                                                 unsigned short* __restrict__ wb) {
    int i = (blockIdx.x * 256 + threadIdx.x) * 4;
    float4 v = *(const float4*)&w[i];
    uint2 pk;
    pk.x = f2bf(v.x) | ((unsigned)f2bf(v.y) << 16);
    pk.y = f2bf(v.z) | ((unsigned)f2bf(v.w) << 16);
    *(uint2*)&wb[i] = pk;
}

// ---------------- wv (rows 1024..1535 of wqkv, (ch,c)) -> wvT (c,ch) bf16 ----------------
__global__ __launch_bounds__(256) void transpose_wv(const float* __restrict__ wqkv,
                                                    unsigned short* __restrict__ wvT) {
    __shared__ float lds[64 * 65];
    const int c0  = blockIdx.x * 64;
    const int ch0 = blockIdx.y * 64;
    const int t   = threadIdx.x;
    const int cl  = (t & 15) * 4;
    const int rl  = t >> 4;
#pragma unroll
    for (int i = 0; i < 4; ++i) {
        int r = rl + i * 16;   // ch row
        float4 v = *(const float4*)&wqkv[((size_t)(1024 + ch0 + r)) * 512 + c0 + cl];
        float* row = &lds[r * 65 + cl];
        row[0] = v.x; row[1] = v.y; row[2] = v.z; row[3] = v.w;
    }
    __syncthreads();
#pragma unroll
    for (int i = 0; i < 2; ++i) {
        int idx = t + i * 256;
        int c = idx >> 3;
        int g = (idx & 7) * 8;
        unsigned v0, v1, v2, v3;
        v0 = f2bf(lds[(g + 0) * 65 + c]) | ((unsigned)f2bf(lds[(g + 1) * 65 + c]) << 16);
        v1 = f2bf(lds[(g + 2) * 65 + c]) | ((unsigned)f2bf(lds[(g + 3) * 65 + c]) << 16);
        v2 = f2bf(lds[(g + 4) * 65 + c]) | ((unsigned)f2bf(lds[(g + 5) * 65 + c]) << 16);
        v3 = f2bf(lds[(g + 6) * 65 + c]) | ((unsigned)f2bf(lds[(g + 7) * 65 + c]) << 16);
        uint4 pk; pk.x = v0; pk.y = v1; pk.z = v2; pk.w = v3;
        *(uint4*)&wvT[((size_t)(c0 + c)) * 512 + ch0 + g] = pk;
    }
}

// ---------------- qk GEMM: (B,N,512) @ (1024,512)^T + bias, relu ----------------
// q -> qbuf (B,512,N) ; k -> kbuf (B,512,N)
__global__ __launch_bounds__(256) void gemm_qkv(
    const unsigned short* __restrict__ xt, const unsigned short* __restrict__ wq,
    const float* __restrict__ bqkv,
    unsigned short* __restrict__ qbuf, unsigned short* __restrict__ kbuf) {
    __shared__ unsigned short Als[128 * 64];
    __shared__ unsigned short Bls[128 * 64];
    const int b  = blockIdx.z;
    const int n0 = blockIdx.x * 128;
    const int j0 = blockIdx.y * 128;
    const int t  = threadIdx.x;
    const int wv = t >> 6, ln = t & 63;
    const unsigned short* Ag = xt + (size_t)(b * NSP + n0) * 512;
    const unsigned short* Bg = wq + (size_t)j0 * 512;

    fragC acc[4][4];
#pragma unroll
    for (int i = 0; i < 4; ++i)
#pragma unroll
        for (int j = 0; j < 4; ++j) { acc[i][j][0]=0.f; acc[i][j][1]=0.f; acc[i][j][2]=0.f; acc[i][j][3]=0.f; }

    const int mw = (wv >> 1) * 64, nw = (wv & 1) * 64;
    const int srow = ln >> 3;
    const int scol = ((ln & 7) ^ srow) << 3;   // swizzled colgroup

    for (int k0 = 0; k0 < 512; k0 += 64) {
#pragma unroll
        for (int i = 0; i < 4; ++i) {
            int chunk = wv * 4 + i;
            int row = chunk * 8 + srow;
            GLD_LDS(Ag + (size_t)row * 512 + k0 + scol, &Als[chunk * 512]);
            GLD_LDS(Bg + (size_t)row * 512 + k0 + scol, &Bls[chunk * 512]);
        }
        __syncthreads();
#pragma unroll
        for (int kk = 0; kk < 64; kk += 32) {
            int g = (kk >> 3) + (ln >> 4);
            fragAB a[4], bf[4];
#pragma unroll
            for (int mt = 0; mt < 4; ++mt) a[mt]  = ldfrag(Als, mw + mt * 16 + (ln & 15), g);
#pragma unroll
            for (int nt = 0; nt < 4; ++nt) bf[nt] = ldfrag(Bls, nw + nt * 16 + (ln & 15), g);
#pragma unroll
            for (int mt = 0; mt < 4; ++mt)
#pragma unroll
                for (int nt = 0; nt < 4; ++nt)
                    acc[mt][nt] = __builtin_amdgcn_mfma_f32_16x16x32_bf16(a[mt], bf[nt], acc[mt][nt], 0, 0, 0);
        }
        __syncthreads();
    }

    unsigned short* dst = (j0 < 512 ? qbuf : kbuf) + (size_t)b * 512 * NSP;
#pragma unroll
    for (int mt = 0; mt < 4; ++mt)
#pragma unroll
        for (int nt = 0; nt < 4; ++nt) {
            int j  = j0 + nw + nt * 16 + (ln & 15);
            int ch = j & 511;
            int n  = n0 + mw + mt * 16 + (ln >> 4) * 4;
            float bias = bqkv[j];
            float r0 = acc[mt][nt][0] + bias; r0 = r0 > 0.f ? r0 : 0.f;
            float r1 = acc[mt][nt][1] + bias; r1 = r1 > 0.f ? r1 : 0.f;
            float r2 = acc[mt][nt][2] + bias; r2 = r2 > 0.f ? r2 : 0.f;
            float r3 = acc[mt][nt][3] + bias; r3 = r3 > 0.f ? r3 : 0.f;
            uint2 pk;
            pk.x = f2bf(r0) | ((unsigned)f2bf(r1) << 16);
            pk.y = f2bf(r2) | ((unsigned)f2bf(r3) << 16);
            *(uint2*)&dst[(size_t)ch * NSP + n] = pk;
        }
}

// ---------------- kq[b,h,c,d] = sum_n k*q  (LDS-staged, split-K atomics) ----------------
__global__ __launch_bounds__(256) void kq_kernel(
    const unsigned short* __restrict__ kbuf, const unsigned short* __restrict__ qbuf,
    float* __restrict__ kq) {
    __shared__ unsigned short Kls[64 * 64];
    __shared__ unsigned short Qls[64 * 64];
    const int bh = blockIdx.x;      // 0..31
    const int chn = blockIdx.y;     // 0..15
    const int t = threadIdx.x, wv = t >> 6, ln = t & 63;
    const unsigned short* Kg = kbuf + (size_t)(bh * 64) * NSP;
    const unsigned short* Qg = qbuf + (size_t)(bh * 64) * NSP;
    fragC acc[4];
#pragma unroll
    for (int i = 0; i < 4; ++i) { acc[i][0]=0.f; acc[i][1]=0.f; acc[i][2]=0.f; acc[i][3]=0.f; }
    const int srow = ln >> 3;
    const int scol = ((ln & 7) ^ srow) << 3;
    const int mA = wv * 16 + (ln & 15);
    const int nbeg = chn * 1024;
    for (int nb = nbeg; nb < nbeg + 1024; nb += 64) {
#pragma unroll
        for (int i = 0; i < 2; ++i) {
            int chunk = wv * 2 + i;
            int row = chunk * 8 + srow;
            GLD_LDS(Kg + (size_t)row * NSP + nb + scol, &Kls[chunk * 512]);
            GLD_LDS(Qg + (size_t)row * NSP + nb + scol, &Qls[chunk * 512]);
        }
        __syncthreads();
#pragma unroll
        for (int kk = 0; kk < 64; kk += 32) {
            int g = (kk >> 3) + (ln >> 4);
            fragAB a = ldfrag(Kls, mA, g);
#pragma unroll
            for (int dt = 0; dt < 4; ++dt) {
                fragAB bq = ldfrag(Qls, dt * 16 + (ln & 15), g);
                acc[dt] = __builtin_amdgcn_mfma_f32_16x16x32_bf16(a, bq, acc[dt], 0, 0, 0);
            }
        }
        __syncthreads();
    }
    float* kqb = kq + bh * 4096;
#pragma unroll
    for (int dt = 0; dt < 4; ++dt) {
        int d = dt * 16 + (ln & 15);
#pragma unroll
        for (int r = 0; r < 4; ++r) {
            int c = wv * 16 + (ln >> 4) * 4 + r;
            atomicAdd(&kqb[c * 64 + d], acc[dt][r]);
        }
    }
}

// ---------------- W2[b,j,h*64+c] = sum_d wout[j,d*8+h]*kq[b,h,c,d]/norm ; bias2 ----------------
__global__ __launch_bounds__(256) void w2_kernel(
    const float* __restrict__ kq, const float* __restrict__ wout,
    const float* __restrict__ bqkv, const float* __restrict__ bout,
    unsigned short* __restrict__ W2, float* __restrict__ bias2) {
    __shared__ float wsc[512];
    __shared__ float red[4];
    const int j = blockIdx.x, b = blockIdx.y, t = threadIdx.x;
    const float* kqb = kq + b * 32768;
#pragma unroll
    for (int i = 0; i < 2; ++i) {
        int idx = t + i * 256;
        int h = idx >> 6, d = idx & 63;
        float s = EPSV;
        for (int c = 0; c < 64; ++c) s += kqb[(h * 64 + c) * 64 + d];
        wsc[idx] = wout[j * 512 + d * 8 + h] / s;
    }
    __syncthreads();
    float part = 0.f;
#pragma unroll
    for (int i = 0; i < 2; ++i) {
        int hc = t + i * 256;
        int h = hc >> 6, c = hc & 63;
        const float* kr = &kqb[(h * 64 + c) * 64];
        const float* wr = &wsc[h * 64];
        float a = 0.f;
        for (int d = 0; d < 64; ++d) a += wr[d] * kr[d];
        W2[((size_t)(b * 512 + j)) * 512 + hc] = f2bf(a);
        part += a * bqkv[1024 + hc];
    }
#pragma unroll
    for (int o = 32; o > 0; o >>= 1) part += __shfl_down(part, o, 64);
    if ((t & 63) == 0) red[t >> 6] = part;
    __syncthreads();
    if (t == 0) bias2[b * 512 + j] = bout[j] + red[0] + red[1] + red[2] + red[3];
}

// ---------------- W3[b,c_rows? ] : W3[b,j,c] = sum_ch W2[b,j,ch]*wvT[c,ch] ----------------
// M = c (A = wvT), N = j (B = W2) -> C-frag rows = c (vectorizable store along c)
__global__ __launch_bounds__(256) void w3_kernel(
    const unsigned short* __restrict__ wvT, const unsigned short* __restrict__ W2,
    unsigned short* __restrict__ W3) {
    __shared__ unsigned short Als[128 * 64];
    __shared__ unsigned short Bls[128 * 64];
    const int b  = blockIdx.z;
    const int m0 = blockIdx.x * 128;   // c
    const int n0 = blockIdx.y * 128;   // j
    const int t  = threadIdx.x;
    const int wv = t >> 6, ln = t & 63;
    const unsigned short* Ag = wvT + (size_t)m0 * 512;
    const unsigned short* Bg = W2 + ((size_t)(b * 512 + n0)) * 512;

    fragC acc[4][4];
#pragma unroll
    for (int i = 0; i < 4; ++i)
#pragma unroll
        for (int j = 0; j < 4; ++j) { acc[i][j][0]=0.f; acc[i][j][1]=0.f; acc[i][j][2]=0.f; acc[i][j][3]=0.f; }

    const int mw = (wv >> 1) * 64, nw = (wv & 1) * 64;
    const int srow = ln >> 3;
    const int scol = ((ln & 7) ^ srow) << 3;

    for (int k0 = 0; k0 < 512; k0 += 64) {
#pragma unroll
        for (int i = 0; i < 4; ++i) {
            int chunk = wv * 4 + i;
            int row = chunk * 8 + srow;
            GLD_LDS(Ag + (size_t)row * 512 + k0 + scol, &Als[chunk * 512]);
            GLD_LDS(Bg + (size_t)row * 512 + k0 + scol, &Bls[chunk * 512]);
        }
        __syncthreads();
#pragma unroll
        for (int kk = 0; kk < 64; kk += 32) {
            int g = (kk >> 3) + (ln >> 4);
            fragAB a[4], bf[4];
#pragma unroll
            for (int mt = 0; mt < 4; ++mt) a[mt]  = ldfrag(Als, mw + mt * 16 + (ln & 15), g);
#pragma unroll
            for (int nt = 0; nt < 4; ++nt) bf[nt] = ldfrag(Bls, nw + nt * 16 + (ln & 15), g);
#pragma unroll
            for (int mt = 0; mt < 4; ++mt)
#pragma unroll
                for (int nt = 0; nt < 4; ++nt)
                    acc[mt][nt] = __builtin_amdgcn_mfma_f32_16x16x32_bf16(a[mt], bf[nt], acc[mt][nt], 0, 0, 0);
        }
        __syncthreads();
    }

#pragma unroll
    for (int mt = 0; mt < 4; ++mt)
#pragma unroll
        for (int nt = 0; nt < 4; ++nt) {
            int c = m0 + mw + mt * 16 + (ln >> 4) * 4;
            int j = n0 + nw + nt * 16 + (ln & 15);
            uint2 pk;
            pk.x = f2bf(acc[mt][nt][0]) | ((unsigned)f2bf(acc[mt][nt][1]) << 16);
            pk.y = f2bf(acc[mt][nt][2]) | ((unsigned)f2bf(acc[mt][nt][3]) << 16);
            *(uint2*)&W3[((size_t)(b * 512 + j)) * 512 + c] = pk;
        }
}

// ---------------- out GEMM: out[b,j,n] = sum_c xt[b,n,c]*W3[b,j,c] + bias2[b,j] ----------------
__global__ __launch_bounds__(256) void gemm_out(
    const unsigned short* __restrict__ xt, const unsigned short* __restrict__ W3,
    const float* __restrict__ bias2, float* __restrict__ out) {
    __shared__ unsigned short Als[128 * 64];
    __shared__ unsigned short Bls[128 * 64];
    const int b  = blockIdx.z;
    const int n0 = blockIdx.x * 128;
    const int j0 = blockIdx.y * 128;
    const int t  = threadIdx.x;
    const int wv = t >> 6, ln = t & 63;
    const unsigned short* Ag = xt + (size_t)(b * NSP + n0) * 512;
    const unsigned short* Bg = W3 + ((size_t)(b * 512 + j0)) * 512;

    fragC acc[4][4];
#pragma unroll
    for (int i = 0; i < 4; ++i)
#pragma unroll
        for (int j = 0; j < 4; ++j) { acc[i][j][0]=0.f; acc[i][j][1]=0.f; acc[i][j][2]=0.f; acc[i][j][3]=0.f; }

    const int mw = (wv >> 1) * 64, nw = (wv & 1) * 64;
    const int srow = ln >> 3;
    const int scol = ((ln & 7) ^ srow) << 3;

    for (int k0 = 0; k0 < 512; k0 += 64) {
#pragma unroll
        for (int i = 0; i < 4; ++i) {
            int chunk = wv * 4 + i;
            int row = chunk * 8 + srow;
            GLD_LDS(Ag + (size_t)row * 512 + k0 + scol, &Als[chunk * 512]);
            GLD_LDS(Bg + (size_t)row * 512 + k0 + scol, &Bls[chunk * 512]);
        }
        __syncthreads();
#pragma unroll
        for (int kk = 0; kk < 64; kk += 32) {
            int g = (kk >> 3) + (ln >> 4);
            fragAB a[4], bf[4];
#pragma unroll
            for (int mt = 0; mt < 4; ++mt) a[mt]  = ldfrag(Als, mw + mt * 16 + (ln & 15), g);
#pragma unroll
            for (int nt = 0; nt < 4; ++nt) bf[nt] = ldfrag(Bls, nw + nt * 16 + (ln & 15), g);
#pragma unroll
            for (int mt = 0; mt < 4; ++mt)
#pragma unroll
                for (int nt = 0; nt < 4; ++nt)
                    acc[mt][nt] = __builtin_amdgcn_mfma_f32_16x16x32_bf16(a[mt], bf[nt], acc[mt][nt], 0, 0, 0);
        }
        __syncthreads();
    }

#pragma unroll
    for (int mt = 0; mt < 4; ++mt)
#pragma unroll
        for (int nt = 0; nt < 4; ++nt) {
            int j = j0 + nw + nt * 16 + (ln & 15);
            int n = n0 + mw + mt * 16 + (ln >> 4) * 4;
            float bias = bias2[b * 512 + j];
            float4 v;
            v.x = acc[mt][nt][0] + bias;
            v.y = acc[mt][nt][1] + bias;
            v.z = acc[mt][nt][2] + bias;
            v.w = acc[mt][nt][3] + bias;
            *(float4*)&out[((size_t)(b * 512 + j)) * NSP + n] = v;
        }
}

extern "C" void kernel_launch(void* const* d_in, const int* in_sizes, int n_in,
                              void* d_out, int out_size, void* d_ws, size_t ws_size,
                              hipStream_t stream) {
    const float* x    = (const float*)d_in[0];
    const float* wqkv = (const float*)d_in[1];
    const float* bqkv = (const float*)d_in[2];
    const float* wout = (const float*)d_in[3];
    const float* bout = (const float*)d_in[4];
    float* out = (float*)d_out;

    char* p = (char*)d_ws;
    unsigned short* xt   = (unsigned short*)p; p += (size_t)BATCH * NSP * 512 * 2;   // 64 MB
    unsigned short* wqb  = (unsigned short*)p; p += (size_t)1024 * 512 * 2;          // 1 MB
    unsigned short* wvT  = (unsigned short*)p; p += (size_t)512 * 512 * 2;           // 0.5 MB
    unsigned short* qbuf = (unsigned short*)p; p += (size_t)BATCH * 512 * NSP * 2;   // 64 MB
    unsigned short* kbuf = (unsigned short*)p; p += (size_t)BATCH * 512 * NSP * 2;   // 64 MB
    float*          kq   = (float*)p;          p += (size_t)BATCH * 32768 * 4;       // 512 KB
    unsigned short* W2   = (unsigned short*)p; p += (size_t)BATCH * 512 * 512 * 2;   // 2 MB
    float*          bias2= (float*)p;          p += (size_t)BATCH * 512 * 4;         // 8 KB
    unsigned short* W3   = (unsigned short*)p; p += (size_t)BATCH * 512 * 512 * 2;   // 2 MB

    hipMemsetAsync(kq, 0, (size_t)BATCH * 32768 * 4, stream);
    transpose_x<<<dim3(256, 8, BATCH), 256, 0, stream>>>(x, xt);
    convert_w<<<dim3(512), 256, 0, stream>>>(wqkv, wqb);
    transpose_wv<<<dim3(8, 8), 256, 0, stream>>>(wqkv, wvT);
    gemm_qkv<<<dim3(128, 8, BATCH), 256, 0, stream>>>(xt, wqb, bqkv, qbuf, kbuf);
    kq_kernel<<<dim3(32, 16), 256, 0, stream>>>(kbuf, qbuf, kq);
    w2_kernel<<<dim3(512, BATCH), 256, 0, stream>>>(kq, wout, bqkv, bout, W2, bias2);
    w3_kernel<<<dim3(4, 4, BATCH), 256, 0, stream>>>(wvT, W2, W3);
    gemm_out<<<dim3(128, 4, BATCH), 256, 0, stream>>>(xt, W3, bias2, out);
}

// Round 3
// 425.134 us; speedup vs baseline: 1.4340x; 1.2220x over previous
//
#include <hip/hip_runtime.h>
#include <hip/hip_bf16.h>
#include <stdint.h>

#define NSP 16384   // 128*128 spatial
#define BATCH 4
#define EPSV 1e-6f

typedef __attribute__((ext_vector_type(8))) short fragAB;   // 8 bf16
typedef __attribute__((ext_vector_type(4))) float fragC;    // 4 fp32

__device__ __forceinline__ unsigned short f2bf(float f) {
    union { float f; unsigned u; } un; un.f = f;
    unsigned r = un.u + 0x7fffu + ((un.u >> 16) & 1u);   // RNE
    return (unsigned short)(r >> 16);
}

#define GLD_LDS(g, l) __builtin_amdgcn_global_load_lds( \
    (const __attribute__((address_space(1))) void*)(g), \
    (__attribute__((address_space(3))) void*)(l), 16, 0, 0)

// XOR-swizzled fragment read (see r1 notes): element (row m, colgroup g) at
// (m>>3)*512 + (m&7)*64 + ((g ^ (m&7))*8); matches global_load_lds lane slots.
__device__ __forceinline__ fragAB ldfrag(const unsigned short* ls, int m, int g) {
    return *(const fragAB*)&ls[((m >> 3) << 9) + ((m & 7) << 6) + ((g ^ (m & 7)) << 3)];
}

// ---------------- x (B,C,N) fp32 -> xt (B,N,C) bf16 ----------------
__global__ __launch_bounds__(256) void transpose_x(const float* __restrict__ x,
                                                   unsigned short* __restrict__ xt) {
    __shared__ float lds[64 * 65];
    const int b  = blockIdx.z;
    const int c0 = blockIdx.y * 64;
    const int n0 = blockIdx.x * 64;
    const int t  = threadIdx.x;
    const int nl = (t & 15) * 4;
    const int cl = t >> 4;
#pragma unroll
    for (int i = 0; i < 4; ++i) {
        int c = cl + i * 16;
        float4 v = *(const float4*)&x[((size_t)(b * 512 + c0 + c)) * NSP + n0 + nl];
        float* row = &lds[c * 65 + nl];
        row[0] = v.x; row[1] = v.y; row[2] = v.z; row[3] = v.w;
    }
    __syncthreads();
#pragma unroll
    for (int i = 0; i < 2; ++i) {
        int ch = t + i * 256;      // 0..511
        int n  = ch >> 3;
        int co = (ch & 7) * 8;
        unsigned v0, v1, v2, v3;
        v0 = f2bf(lds[(co + 0) * 65 + n]) | ((unsigned)f2bf(lds[(co + 1) * 65 + n]) << 16);
        v1 = f2bf(lds[(co + 2) * 65 + n]) | ((unsigned)f2bf(lds[(co + 3) * 65 + n]) << 16);
        v2 = f2bf(lds[(co + 4) * 65 + n]) | ((unsigned)f2bf(lds[(co + 5) * 65 + n]) << 16);
        v3 = f2bf(lds[(co + 6) * 65 + n]) | ((unsigned)f2bf(lds[(co + 7) * 65 + n]) << 16);
        uint4 pk; pk.x = v0; pk.y = v1; pk.z = v2; pk.w = v3;
        *(uint4*)&xt[((size_t)(b * NSP + n0 + n)) * 512 + c0 + co] = pk;
    }
}

// ---------------- prep: convert wqkv rows 0..1023 -> bf16 ; wv rows -> wvT ----------------
__global__ __launch_bounds__(256) void prep(const float* __restrict__ wqkv,
                                            unsigned short* __restrict__ wqb,
                                            unsigned short* __restrict__ wvT) {
    __shared__ float lds[64 * 65];
    const int blk = blockIdx.x;
    const int t   = threadIdx.x;
    if (blk < 512) {
        int i = (blk * 256 + t) * 4;
        float4 v = *(const float4*)&wqkv[i];
        uint2 pk;
        pk.x = f2bf(v.x) | ((unsigned)f2bf(v.y) << 16);
        pk.y = f2bf(v.z) | ((unsigned)f2bf(v.w) << 16);
        *(uint2*)&wqb[i] = pk;
        return;
    }
    const int c0  = ((blk - 512) & 7) * 64;
    const int ch0 = ((blk - 512) >> 3) * 64;
    const int cl  = (t & 15) * 4;
    const int rl  = t >> 4;
#pragma unroll
    for (int i = 0; i < 4; ++i) {
        int r = rl + i * 16;   // ch row
        float4 v = *(const float4*)&wqkv[((size_t)(1024 + ch0 + r)) * 512 + c0 + cl];
        float* row = &lds[r * 65 + cl];
        row[0] = v.x; row[1] = v.y; row[2] = v.z; row[3] = v.w;
    }
    __syncthreads();
#pragma unroll
    for (int i = 0; i < 2; ++i) {
        int idx = t + i * 256;
        int c = idx >> 3;
        int g = (idx & 7) * 8;
        unsigned v0, v1, v2, v3;
        v0 = f2bf(lds[(g + 0) * 65 + c]) | ((unsigned)f2bf(lds[(g + 1) * 65 + c]) << 16);
        v1 = f2bf(lds[(g + 2) * 65 + c]) | ((unsigned)f2bf(lds[(g + 3) * 65 + c]) << 16);
        v2 = f2bf(lds[(g + 4) * 65 + c]) | ((unsigned)f2bf(lds[(g + 5) * 65 + c]) << 16);
        v3 = f2bf(lds[(g + 6) * 65 + c]) | ((unsigned)f2bf(lds[(g + 7) * 65 + c]) << 16);
        uint4 pk; pk.x = v0; pk.y = v1; pk.z = v2; pk.w = v3;
        *(uint4*)&wvT[((size_t)(c0 + c)) * 512 + ch0 + g] = pk;
    }
}

// ---------------- qk GEMM: 128n x 256j blocks, wave tile 128x64 ----------------
// q -> qbuf (B,512,N) relu ; k -> kbuf (B,512,N) relu
__global__ __launch_bounds__(256, 2) void gemm_qkv(
    const unsigned short* __restrict__ xt, const unsigned short* __restrict__ wq,
    const float* __restrict__ bqkv,
    unsigned short* __restrict__ qbuf, unsigned short* __restrict__ kbuf) {
    __shared__ unsigned short Als[128 * 64];
    __shared__ unsigned short Bls[256 * 64];
    const int b  = blockIdx.z;
    const int n0 = blockIdx.x * 128;
    const int j0 = blockIdx.y * 256;
    const int t  = threadIdx.x;
    const int wv = t >> 6, ln = t & 63;
    const unsigned short* Ag = xt + (size_t)(b * NSP + n0) * 512;
    const unsigned short* Bg = wq + (size_t)j0 * 512;

    fragC acc[8][4];
#pragma unroll
    for (int i = 0; i < 8; ++i)
#pragma unroll
        for (int j = 0; j < 4; ++j) { acc[i][j][0]=0.f; acc[i][j][1]=0.f; acc[i][j][2]=0.f; acc[i][j][3]=0.f; }

    const int srow = ln >> 3;
    const int scol = ((ln & 7) ^ srow) << 3;

    for (int k0 = 0; k0 < 512; k0 += 64) {
#pragma unroll
        for (int i = 0; i < 4; ++i) {
            int ca = wv * 4 + i;
            GLD_LDS(Ag + (size_t)(ca * 8 + srow) * 512 + k0 + scol, &Als[ca * 512]);
        }
#pragma unroll
        for (int i = 0; i < 8; ++i) {
            int cb = wv * 8 + i;
            GLD_LDS(Bg + (size_t)(cb * 8 + srow) * 512 + k0 + scol, &Bls[cb * 512]);
        }
        __syncthreads();
#pragma unroll
        for (int kk = 0; kk < 64; kk += 32) {
            int g = (kk >> 3) + (ln >> 4);
            fragAB bf[4];
#pragma unroll
            for (int nt = 0; nt < 4; ++nt) bf[nt] = ldfrag(Bls, wv * 64 + nt * 16 + (ln & 15), g);
#pragma unroll
            for (int mt = 0; mt < 8; ++mt) {
                fragAB a = ldfrag(Als, mt * 16 + (ln & 15), g);
#pragma unroll
                for (int nt = 0; nt < 4; ++nt)
                    acc[mt][nt] = __builtin_amdgcn_mfma_f32_16x16x32_bf16(a, bf[nt], acc[mt][nt], 0, 0, 0);
            }
        }
        __syncthreads();
    }

    unsigned short* dst = (j0 < 512 ? qbuf : kbuf) + (size_t)b * 512 * NSP;
#pragma unroll
    for (int nt = 0; nt < 4; ++nt) {
        int j  = j0 + wv * 64 + nt * 16 + (ln & 15);
        int ch = j & 511;
        float bias = bqkv[j];
#pragma unroll
        for (int mt = 0; mt < 8; ++mt) {
            int n = n0 + mt * 16 + (ln >> 4) * 4;
            float r0 = acc[mt][nt][0] + bias; r0 = r0 > 0.f ? r0 : 0.f;
            float r1 = acc[mt][nt][1] + bias; r1 = r1 > 0.f ? r1 : 0.f;
            float r2 = acc[mt][nt][2] + bias; r2 = r2 > 0.f ? r2 : 0.f;
            float r3 = acc[mt][nt][3] + bias; r3 = r3 > 0.f ? r3 : 0.f;
            uint2 pk;
            pk.x = f2bf(r0) | ((unsigned)f2bf(r1) << 16);
            pk.y = f2bf(r2) | ((unsigned)f2bf(r3) << 16);
            *(uint2*)&dst[(size_t)ch * NSP + n] = pk;
        }
    }
}

// ---------------- kq[b,h,c,d] = sum_n k*q  (LDS-staged, split-K atomics) ----------------
__global__ __launch_bounds__(256) void kq_kernel(
    const unsigned short* __restrict__ kbuf, const unsigned short* __restrict__ qbuf,
    float* __restrict__ kq) {
    __shared__ unsigned short Kls[64 * 64];
    __shared__ unsigned short Qls[64 * 64];
    const int bh = blockIdx.x;      // 0..31
    const int chn = blockIdx.y;     // 0..15
    const int t = threadIdx.x, wv = t >> 6, ln = t & 63;
    const unsigned short* Kg = kbuf + (size_t)(bh * 64) * NSP;
    const unsigned short* Qg = qbuf + (size_t)(bh * 64) * NSP;
    fragC acc[4];
#pragma unroll
    for (int i = 0; i < 4; ++i) { acc[i][0]=0.f; acc[i][1]=0.f; acc[i][2]=0.f; acc[i][3]=0.f; }
    const int srow = ln >> 3;
    const int scol = ((ln & 7) ^ srow) << 3;
    const int mA = wv * 16 + (ln & 15);
    const int nbeg = chn * 1024;
    for (int nb = nbeg; nb < nbeg + 1024; nb += 64) {
#pragma unroll
        for (int i = 0; i < 2; ++i) {
            int chunk = wv * 2 + i;
            int row = chunk * 8 + srow;
            GLD_LDS(Kg + (size_t)row * NSP + nb + scol, &Kls[chunk * 512]);
            GLD_LDS(Qg + (size_t)row * NSP + nb + scol, &Qls[chunk * 512]);
        }
        __syncthreads();
#pragma unroll
        for (int kk = 0; kk < 64; kk += 32) {
            int g = (kk >> 3) + (ln >> 4);
            fragAB a = ldfrag(Kls, mA, g);
#pragma unroll
            for (int dt = 0; dt < 4; ++dt) {
                fragAB bq = ldfrag(Qls, dt * 16 + (ln & 15), g);
                acc[dt] = __builtin_amdgcn_mfma_f32_16x16x32_bf16(a, bq, acc[dt], 0, 0, 0);
            }
        }
        __syncthreads();
    }
    float* kqb = kq + bh * 4096;
#pragma unroll
    for (int dt = 0; dt < 4; ++dt) {
        int d = dt * 16 + (ln & 15);
#pragma unroll
        for (int r = 0; r < 4; ++r) {
            int c = wv * 16 + (ln >> 4) * 4 + r;
            atomicAdd(&kqb[c * 64 + d], acc[dt][r]);
        }
    }
}

// ---------------- W2 via LDS slab: block = (j-chunk 32, h, b) ----------------
// W2[b,j,h*64+c] = sum_d wout[j,d*8+h]*kq[b,h,c,d]/norm[d] ; bias2acc += W2 . bv
__global__ __launch_bounds__(256) void w2_kernel(
    const float* __restrict__ kq, const float* __restrict__ wout,
    const float* __restrict__ bqkv,
    unsigned short* __restrict__ W2, float* __restrict__ bias2acc) {
    __shared__ float slab[64 * 65];   // [c][d] padded
    __shared__ float part[4 * 64];
    __shared__ float rnorm[64];
    __shared__ float wsc[32 * 65];    // [jl][d] padded
    const int jc = blockIdx.x;   // j0 = jc*32
    const int h  = blockIdx.y;
    const int b  = blockIdx.z;
    const int t  = threadIdx.x;
    const float* kqb = kq + ((size_t)(b * 8 + h)) * 4096;
#pragma unroll
    for (int i = 0; i < 4; ++i) {
        int e = t * 16 + i * 4;
        float4 v = *(const float4*)&kqb[e];
        float* r = &slab[(e >> 6) * 65 + (e & 63)];
        r[0] = v.x; r[1] = v.y; r[2] = v.z; r[3] = v.w;
    }
    __syncthreads();
    {
        int d = t & 63, cq = t >> 6;
        float s = 0.f;
        for (int c = cq * 16; c < cq * 16 + 16; ++c) s += slab[c * 65 + d];
        part[cq * 64 + d] = s;
    }
    __syncthreads();
    if (t < 64) rnorm[t] = 1.0f / (part[t] + part[64 + t] + part[128 + t] + part[192 + t] + EPSV);
    __syncthreads();
    {
        int jl = t >> 3;
        const float* wrow = &wout[((size_t)(jc * 32 + jl)) * 512 + h];
#pragma unroll
        for (int i = 0; i < 8; ++i) {
            int d = (t & 7) * 8 + i;
            wsc[jl * 65 + d] = wrow[d * 8] * rnorm[d];
        }
    }
    __syncthreads();
    {
        int jl = t >> 3, cg = (t & 7) * 8;
        int j  = jc * 32 + jl;
        float a[8] = {0.f, 0.f, 0.f, 0.f, 0.f, 0.f, 0.f, 0.f};
        for (int d = 0; d < 64; ++d) {
            float w = wsc[jl * 65 + d];
#pragma unroll
            for (int i = 0; i < 8; ++i) a[i] += w * slab[(cg + i) * 65 + d];
        }
        uint4 pk;
        pk.x = f2bf(a[0]) | ((unsigned)f2bf(a[1]) << 16);
        pk.y = f2bf(a[2]) | ((unsigned)f2bf(a[3]) << 16);
        pk.z = f2bf(a[4]) | ((unsigned)f2bf(a[5]) << 16);
        pk.w = f2bf(a[6]) | ((unsigned)f2bf(a[7]) << 16);
        *(uint4*)&W2[((size_t)(b * 512 + j)) * 512 + h * 64 + cg] = pk;
        const float* bv = &bqkv[1024 + h * 64 + cg];
        float p = 0.f;
#pragma unroll
        for (int i = 0; i < 8; ++i) p += a[i] * bv[i];
        p += __shfl_down(p, 4, 64);
        p += __shfl_down(p, 2, 64);
        p += __shfl_down(p, 1, 64);
        if ((t & 7) == 0) atomicAdd(&bias2acc[b * 512 + j], p);
    }
}

// ---------------- W3[b,j,c] = sum_ch wvT[c,ch]*W2[b,j,ch] ----------------
__global__ __launch_bounds__(256) void w3_kernel(
    const unsigned short* __restrict__ wvT, const unsigned short* __restrict__ W2,
    unsigned short* __restrict__ W3) {
    __shared__ unsigned short Als[128 * 64];
    __shared__ unsigned short Bls[128 * 64];
    const int b  = blockIdx.z;
    const int m0 = blockIdx.x * 128;   // c
    const int n0 = blockIdx.y * 128;   // j
    const int t  = threadIdx.x;
    const int wv = t >> 6, ln = t & 63;
    const unsigned short* Ag = wvT + (size_t)m0 * 512;
    const unsigned short* Bg = W2 + ((size_t)(b * 512 + n0)) * 512;

    fragC acc[4][4];
#pragma unroll
    for (int i = 0; i < 4; ++i)
#pragma unroll
        for (int j = 0; j < 4; ++j) { acc[i][j][0]=0.f; acc[i][j][1]=0.f; acc[i][j][2]=0.f; acc[i][j][3]=0.f; }

    const int mw = (wv >> 1) * 64, nw = (wv & 1) * 64;
    const int srow = ln >> 3;
    const int scol = ((ln & 7) ^ srow) << 3;

    for (int k0 = 0; k0 < 512; k0 += 64) {
#pragma unroll
        for (int i = 0; i < 4; ++i) {
            int chunk = wv * 4 + i;
            int row = chunk * 8 + srow;
            GLD_LDS(Ag + (size_t)row * 512 + k0 + scol, &Als[chunk * 512]);
            GLD_LDS(Bg + (size_t)row * 512 + k0 + scol, &Bls[chunk * 512]);
        }
        __syncthreads();
#pragma unroll
        for (int kk = 0; kk < 64; kk += 32) {
            int g = (kk >> 3) + (ln >> 4);
            fragAB a[4], bf[4];
#pragma unroll
            for (int mt = 0; mt < 4; ++mt) a[mt]  = ldfrag(Als, mw + mt * 16 + (ln & 15), g);
#pragma unroll
            for (int nt = 0; nt < 4; ++nt) bf[nt] = ldfrag(Bls, nw + nt * 16 + (ln & 15), g);
#pragma unroll
            for (int mt = 0; mt < 4; ++mt)
#pragma unroll
                for (int nt = 0; nt < 4; ++nt)
                    acc[mt][nt] = __builtin_amdgcn_mfma_f32_16x16x32_bf16(a[mt], bf[nt], acc[mt][nt], 0, 0, 0);
        }
        __syncthreads();
    }

#pragma unroll
    for (int mt = 0; mt < 4; ++mt)
#pragma unroll
        for (int nt = 0; nt < 4; ++nt) {
            int c = m0 + mw + mt * 16 + (ln >> 4) * 4;
            int j = n0 + nw + nt * 16 + (ln & 15);
            uint2 pk;
            pk.x = f2bf(acc[mt][nt][0]) | ((unsigned)f2bf(acc[mt][nt][1]) << 16);
            pk.y = f2bf(acc[mt][nt][2]) | ((unsigned)f2bf(acc[mt][nt][3]) << 16);
            *(uint2*)&W3[((size_t)(b * 512 + j)) * 512 + c] = pk;
        }
}

// ---------------- out GEMM: 128n x 256j blocks, wave tile 128x64 ----------------
__global__ __launch_bounds__(256, 2) void gemm_out(
    const unsigned short* __restrict__ xt, const unsigned short* __restrict__ W3,
    const float* __restrict__ bias2acc, const float* __restrict__ bout,
    float* __restrict__ out) {
    __shared__ unsigned short Als[128 * 64];
    __shared__ unsigned short Bls[256 * 64];
    const int b  = blockIdx.z;
    const int n0 = blockIdx.x * 128;
    const int j0 = blockIdx.y * 256;
    const int t  = threadIdx.x;
    const int wv = t >> 6, ln = t & 63;
    const unsigned short* Ag = xt + (size_t)(b * NSP + n0) * 512;
    const unsigned short* Bg = W3 + ((size_t)(b * 512 + j0)) * 512;

    fragC acc[8][4];
#pragma unroll
    for (int i = 0; i < 8; ++i)
#pragma unroll
        for (int j = 0; j < 4; ++j) { acc[i][j][0]=0.f; acc[i][j][1]=0.f; acc[i][j][2]=0.f; acc[i][j][3]=0.f; }

    const int srow = ln >> 3;
    const int scol = ((ln & 7) ^ srow) << 3;

    for (int k0 = 0; k0 < 512; k0 += 64) {
#pragma unroll
        for (int i = 0; i < 4; ++i) {
            int ca = wv * 4 + i;
            GLD_LDS(Ag + (size_t)(ca * 8 + srow) * 512 + k0 + scol, &Als[ca * 512]);
        }
#pragma unroll
        for (int i = 0; i < 8; ++i) {
            int cb = wv * 8 + i;
            GLD_LDS(Bg + (size_t)(cb * 8 + srow) * 512 + k0 + scol, &Bls[cb * 512]);
        }
        __syncthreads();
#pragma unroll
        for (int kk = 0; kk < 64; kk += 32) {
            int g = (kk >> 3) + (ln >> 4);
            fragAB bf[4];
#pragma unroll
            for (int nt = 0; nt < 4; ++nt) bf[nt] = ldfrag(Bls, wv * 64 + nt * 16 + (ln & 15), g);
#pragma unroll
            for (int mt = 0; mt < 8; ++mt) {
                fragAB a = ldfrag(Als, mt * 16 + (ln & 15), g);
#pragma unroll
                for (int nt = 0; nt < 4; ++nt)
                    acc[mt][nt] = __builtin_amdgcn_mfma_f32_16x16x32_bf16(a, bf[nt], acc[mt][nt], 0, 0, 0);
            }
        }
        __syncthreads();
    }

#pragma unroll
    for (int nt = 0; nt < 4; ++nt) {
        int j = j0 + wv * 64 + nt * 16 + (ln & 15);
        float bias = bout[j] + bias2acc[b * 512 + j];
#pragma unroll
        for (int mt = 0; mt < 8; ++mt) {
            int n = n0 + mt * 16 + (ln >> 4) * 4;
            float4 v;
            v.x = acc[mt][nt][0] + bias;
            v.y = acc[mt][nt][1] + bias;
            v.z = acc[mt][nt][2] + bias;
            v.w = acc[mt][nt][3] + bias;
            *(float4*)&out[((size_t)(b * 512 + j)) * NSP + n] = v;
        }
    }
}

extern "C" void kernel_launch(void* const* d_in, const int* in_sizes, int n_in,
                              void* d_out, int out_size, void* d_ws, size_t ws_size,
                              hipStream_t stream) {
    const float* x    = (const float*)d_in[0];
    const float* wqkv = (const float*)d_in[1];
    const float* bqkv = (const float*)d_in[2];
    const float* wout = (const float*)d_in[3];
    const float* bout = (const float*)d_in[4];
    float* out = (float*)d_out;

    char* p = (char*)d_ws;
    unsigned short* xt   = (unsigned short*)p; p += (size_t)BATCH * NSP * 512 * 2;   // 64 MB
    unsigned short* wqb  = (unsigned short*)p; p += (size_t)1024 * 512 * 2;          // 1 MB
    unsigned short* wvT  = (unsigned short*)p; p += (size_t)512 * 512 * 2;           // 0.5 MB
    unsigned short* qbuf = (unsigned short*)p; p += (size_t)BATCH * 512 * NSP * 2;   // 64 MB
    unsigned short* kbuf = (unsigned short*)p; p += (size_t)BATCH * 512 * NSP * 2;   // 64 MB
    float*          kq   = (float*)p;          p += (size_t)BATCH * 32768 * 4;       // 512 KB
    float*          b2a  = (float*)p;          p += (size_t)BATCH * 512 * 4;         // 8 KB (adjacent to kq)
    unsigned short* W2   = (unsigned short*)p; p += (size_t)BATCH * 512 * 512 * 2;   // 2 MB
    unsigned short* W3   = (unsigned short*)p; p += (size_t)BATCH * 512 * 512 * 2;   // 2 MB

    hipMemsetAsync(kq, 0, (size_t)BATCH * 32768 * 4 + (size_t)BATCH * 512 * 4, stream);
    transpose_x<<<dim3(256, 8, BATCH), 256, 0, stream>>>(x, xt);
    prep<<<dim3(576), 256, 0, stream>>>(wqkv, wqb, wvT);
    gemm_qkv<<<dim3(128, 4, BATCH), 256, 0, stream>>>(xt, wqb, bqkv, qbuf, kbuf);
    kq_kernel<<<dim3(32, 16), 256, 0, stream>>>(kbuf, qbuf, kq);
    w2_kernel<<<dim3(16, 8, BATCH), 256, 0, stream>>>(kq, wout, bqkv, W2, b2a);
    w3_kernel<<<dim3(4, 4, BATCH), 256, 0, stream>>>(wvT, W2, W3);
    gemm_out<<<dim3(128, 2, BATCH), 256, 0, stream>>>(xt, W3, b2a, bout, out);
}